// Round 15
// baseline (77.039 us; speedup 1.0000x reference)
//
#include <hip/hip_runtime.h>
#include <hip/hip_bf16.h>

#define OC    96
#define IH    224
#define IW    224
#define OHH   112
#define OWW   112
#define NIMG  16

typedef __attribute__((ext_vector_type(8))) short bf16x8;
typedef __attribute__((ext_vector_type(4))) float f32x4;

static __device__ inline unsigned short f2bf(float f) {
    // round-to-nearest-even bf16 (off hot path)
    unsigned int u = __float_as_uint(f);
    unsigned int rounded = u + 0x7fff + ((u >> 16) & 1);
    return (unsigned short)(rounded >> 16);
}

static __device__ inline unsigned pkbf(float a, float b) {
    // packed f32x2 -> bf16x2 (v_cvt_pk_bf16_f32), RNE — same values as f2bf
    float2 v; v.x = a; v.y = b;
    __hip_bfloat162 h = __float22bfloat162_rn(v);
    union { __hip_bfloat162 h; unsigned u; } cv;
    cv.h = h;
    return cv.u;
}

// ---------------- K1: renorm + prepack weights into MFMA fragment order (~3 us) -------
__global__ __launch_bounds__(64) void wfrag_kernel(const float* __restrict__ w,
                                                   uint4* __restrict__ wfrag) {
    const int oc   = blockIdx.x;
    const int lane = threadIdx.x;
    const float* wr = w + oc * 147;

    float ssq = 0.f;
    for (int k = lane; k < 147; k += 64) {
        float v = wr[k];
        ssq += v * v;
    }
    #pragma unroll
    for (int off = 32; off > 0; off >>= 1) ssq += __shfl_xor(ssq, off, 64);
    const float rms   = sqrtf(ssq * (1.0f / 147.0f));
    const float scale = (rms > 0.1f) ? (0.1f / rms) : 1.0f;

    if (lane < 24) {
        const int ch = lane >> 2;
        const int u  = lane & 3;
        const int U  = ch * 4 + u;
        unsigned short h[8];
        #pragma unroll
        for (int j = 0; j < 8; ++j) {
            float val = 0.f;
            if (U < 21 && j < 7) {
                int c  = U / 7;
                int kh = U - 7 * c;
                val = wr[c * 49 + kh * 7 + j] * scale;
            }
            h[j] = f2bf(val);
        }
        uint4 o;
        o.x = (unsigned)h[0] | ((unsigned)h[1] << 16);
        o.y = (unsigned)h[2] | ((unsigned)h[3] << 16);
        o.z = (unsigned)h[4] | ((unsigned)h[5] << 16);
        o.w = (unsigned)h[6] | ((unsigned)h[7] << 16);
        const int oct = oc >> 4;
        wfrag[((oct * 6 + ch) * 64) + (u * 16) + (oc & 15)] = o;
    }
}

// ---------------- K2: conv via bf16 MFMA — oh-32 tile + packed cvt --------------------
// Block = 48 ocs x (16 ow x 32 oh). Wave = 4 oh rows (acc[3][4]); swf b128 reads feed
// 4 MFMAs each (was 2); fragment cvt via v_cvt_pk. LDS 51.5 KB -> 2 blocks/CU.
#define PROWS 69
#define PCOLS 40
#define CSTR  (PROWS * PCOLS)   // 2760

__global__ __launch_bounds__(512, 4) void conv_mfma_kernel(const float* __restrict__ x,
                                                           const uint4* __restrict__ wfrag,
                                                           const float* __restrict__ bias,
                                                           unsigned short* __restrict__ ypb) {
    __shared__ float patch[3 * CSTR];     // 33.1 KB
    __shared__ uint4 swf[18 * 64];        // 18.4 KB

    const int tid  = threadIdx.x;
    const int bx   = blockIdx.x;          // 28 px tiles: tx = bx%7 (ow), ty = bx/7 (oh/32)
    const int img  = blockIdx.y;
    const int hf   = blockIdx.z;          // oc half
    const int tx = bx % 7, ty = bx / 7;
    const int ow0 = 16 * tx, oh0 = 32 * ty;
    const int ih0 = 2 * oh0 - 3, iwb = 2 * ow0 - 3;
    const float* xim = x + (size_t)img * 3 * IH * IW;

    // ---- stage this half's weight fragments ----
    {
        const uint4* src = wfrag + hf * (18 * 64);
        for (int i = tid; i < 18 * 64; i += 512) swf[i] = src[i];
    }

    // ---- stage f32 patch [3][69][40] (rows beyond image zero-filled; ty=3 tail ok) ----
    for (int i = tid; i < 3 * CSTR; i += 512) {
        int c   = i / CSTR;
        int rem = i - c * CSTR;
        int r   = rem / PCOLS;
        int cc  = rem - r * PCOLS;
        int ih = ih0 + r, iw = iwb + cc;
        float v = 0.f;
        if ((unsigned)ih < IH && (unsigned)iw < IW) v = xim[(c * IH + ih) * IW + iw];
        patch[i] = v;
    }

    const int wv   = tid >> 6;            // wave -> 4 oh rows starting at oh0 + 4*wv
    const int lane = tid & 63;
    const int m    = lane & 15;           // MFMA col: oc-within-tile AND A-row ow index
    const int u    = lane >> 4;           // k-subgroup

    f32x4 acc[3][4];
    #pragma unroll
    for (int a = 0; a < 3; ++a)
        #pragma unroll
        for (int nt = 0; nt < 4; ++nt) acc[a][nt] = (f32x4){0.f, 0.f, 0.f, 0.f};

    __syncthreads();

    #pragma unroll 1
    for (int ch = 0; ch < 6; ++ch) {
        const int U   = 4 * ch + u;
        const int cq  = (U >= 7) + (U >= 14);
        const int khq = U - 7 * cq;
        const int rbase = (U < 21) ? (cq * CSTR + khq * PCOLS) : 0;

        bf16x8 xfr[4];
        #pragma unroll
        for (int nt = 0; nt < 4; ++nt) {
            const float* bp = &patch[rbase + (8 * wv + 2 * nt) * PCOLS + 2 * m];
            float2 p0 = *(const float2*)(bp + 0);
            float2 p1 = *(const float2*)(bp + 2);
            float2 p2 = *(const float2*)(bp + 4);
            float2 p3 = *(const float2*)(bp + 6);
            uint4 uu;
            uu.x = pkbf(p0.x, p0.y);
            uu.y = pkbf(p1.x, p1.y);
            uu.z = pkbf(p2.x, p2.y);
            uu.w = pkbf(p3.x, p3.y);
            xfr[nt] = *(bf16x8*)&uu;
        }
        #pragma unroll
        for (int a = 0; a < 3; ++a) {
            uint4 wc = swf[(a * 6 + ch) * 64 + lane];
            bf16x8 wfr = *(bf16x8*)&wc;
            #pragma unroll
            for (int nt = 0; nt < 4; ++nt)
                acc[a][nt] = __builtin_amdgcn_mfma_f32_16x16x32_bf16(xfr[nt], wfr, acc[a][nt], 0, 0, 0);
        }
    }

    // ---- epilogue: bias + packed bf16 stores (guard ragged ty=3 rows) ----
    const int ow = ow0 + u * 4;
    #pragma unroll
    for (int a = 0; a < 3; ++a) {
        const int oc = (hf * 3 + a) * 16 + m;
        const float bv = bias[oc];
        #pragma unroll
        for (int nt = 0; nt < 4; ++nt) {
            const int oh = oh0 + 4 * wv + nt;
            if (oh < OHH) {
                uint2 st;
                st.x = pkbf(acc[a][nt][0] + bv, acc[a][nt][1] + bv);
                st.y = pkbf(acc[a][nt][2] + bv, acc[a][nt][3] + bv);
                *(uint2*)(ypb + (((size_t)img * OC + oc) * OHH + oh) * OWW + ow) = st;
            }
        }
    }
}

// ---------------- K3: LDS-free fused LCN + relu + maxpool (R12-proven config) ---------
__global__ __launch_bounds__(256, 4) void lcn_pool_kernel(const unsigned short* __restrict__ y,
                                                          float* __restrict__ outp,
                                                          float* __restrict__ prep,
                                                          float* __restrict__ idxp) {
    const int tid   = threadIdx.x;
    const int band  = tid >> 6;
    const int lane  = tid & 63;
    const int plane = blockIdx.x;
    const int r0    = band * 28;
    const int c0    = lane * 2;
    const bool colv = (lane < 56);

    const unsigned short* yp = y + (size_t)plane * (OHH * OWW);
    float* pp  = prep + (size_t)plane * (OHH * OWW);
    float* op_ = outp + (size_t)plane * (56 * 56);
    float* ip_ = idxp + (size_t)plane * (56 * 56);

    const int lm = (lane + 63) & 63;
    const int lp = (lane + 1) & 63;

    float2 hs0{0,0}, hs1{0,0}, hs2{0,0}, hs3{0,0}, hs4{0,0};
    float2 q0{0,0},  q1{0,0},  q2{0,0},  q3{0,0},  q4{0,0};
    float2 y0{0,0},  y1{0,0},  y2{0,0};
    float2 ct0{0,0}, ct1{0,0}, ct2{0,0};
    float2 prev{0,0};

    #pragma unroll
    for (int i = 0; i < 36; ++i) {
        const int irow = r0 - 4 + i;
        float2 v = {0.f, 0.f};
        if ((unsigned)irow < OHH && colv) {
            unsigned int pr = *(const unsigned int*)(yp + irow * OWW + c0);
            v.x = __uint_as_float(pr << 16);
            v.y = __uint_as_float(pr & 0xffff0000u);
        }

        float Lx = __shfl(v.x, lm, 64), Ly = __shfl(v.y, lm, 64);
        float Rx = __shfl(v.x, lp, 64), Ry = __shfl(v.y, lp, 64);
        float2 hs_new;
        hs_new.x = Lx + Ly + v.x + v.y + Rx;
        hs_new.y = Ly + v.x + v.y + Rx + Ry;
        hs0 = hs1; hs1 = hs2; hs2 = hs3; hs3 = hs4; hs4 = hs_new;
        y0 = y1; y1 = y2; y2 = v;

        if (i >= 4) {
            const int mrow = irow - 2;
            float2 mean;
            mean.x = (hs0.x + hs1.x + hs2.x + hs3.x + hs4.x) * 0.04f;
            mean.y = (hs0.y + hs1.y + hs2.y + hs3.y + hs4.y) * 0.04f;
            float2 ct;
            ct.x = y0.x - mean.x;
            ct.y = y0.y - mean.y;
            if ((unsigned)mrow >= OHH || !colv) { ct.x = 0.f; ct.y = 0.f; }

            float cLx = __shfl(ct.x, lm, 64), cLy = __shfl(ct.y, lm, 64);
            float cRx = __shfl(ct.x, lp, 64), cRy = __shfl(ct.y, lp, 64);
            float2 q_new;
            q_new.x = cLx*cLx + cLy*cLy + ct.x*ct.x + ct.y*ct.y + cRx*cRx;
            q_new.y = cLy*cLy + ct.x*ct.x + ct.y*ct.y + cRx*cRx + cRy*cRy;
            q0 = q1; q1 = q2; q2 = q3; q3 = q4; q4 = q_new;
            ct0 = ct1; ct1 = ct2; ct2 = ct;

            if (i >= 8) {
                const int o = irow - 4;
                float sx = q0.x + q1.x + q2.x + q3.x + q4.x;
                float sy = q0.y + q1.y + q2.y + q3.y + q4.y;
                float vx = fmaxf(ct0.x * rsqrtf(fmaf(sx, 0.04f, 1.0f)), 0.f);
                float vy = fmaxf(ct0.y * rsqrtf(fmaf(sy, 0.04f, 1.0f)), 0.f);
                if (colv) {
                    float2 pv = {vx, vy};
                    *(float2*)(pp + o * OWW + c0) = pv;
                }
                if (o & 1) {
                    float best = prev.x; int loc = 0;
                    if (prev.y > best) { best = prev.y; loc = 1; }
                    if (vx     > best) { best = vx;     loc = 2; }
                    if (vy     > best) { best = vy;     loc = 3; }
                    int idx = (o - 1 + (loc >> 1)) * OWW + (c0 + (loc & 1));
                    if (colv) {
                        size_t oo = (size_t)(o >> 1) * 56 + lane;
                        op_[oo] = best;
                        ip_[oo] = (float)idx;
                    }
                }
                prev.x = vx; prev.y = vy;
            }
        }
    }
}

extern "C" void kernel_launch(void* const* d_in, const int* in_sizes, int n_in,
                              void* d_out, int out_size, void* d_ws, size_t ws_size,
                              hipStream_t stream) {
    const float* x    = (const float*)d_in[0];
    const float* w    = (const float*)d_in[1];
    const float* bias = (const float*)d_in[2];

    unsigned short* y = (unsigned short*)d_ws;                  // 19,267,584 bf16 = 38.5 MB
    uint4* wfrag = (uint4*)((char*)d_ws + (size_t)NIMG * OC * OHH * OWW * 2);  // 36,864 B

    float* outp = (float*)d_out;                                // [16,96,56,56]
    float* prep = outp + (size_t)NIMG * OC * 56 * 56;           // [16,96,112,112]
    float* idxp = prep + (size_t)NIMG * OC * OHH * OWW;         // [16,96,56,56]

    wfrag_kernel<<<dim3(OC), dim3(64), 0, stream>>>(w, wfrag);
    conv_mfma_kernel<<<dim3(28, NIMG, 2), dim3(512), 0, stream>>>(x, wfrag, bias, y);
    lcn_pool_kernel<<<dim3(NIMG * OC), dim3(256), 0, stream>>>(y, outp, prep, idxp);
}

// Round 16
// 70.972 us; speedup vs baseline: 1.0855x; 1.0855x over previous
//
#include <hip/hip_runtime.h>
#include <hip/hip_bf16.h>

#define OC    96
#define IH    224
#define IW    224
#define OHH   112
#define OWW   112
#define NIMG  16

typedef __attribute__((ext_vector_type(8))) short bf16x8;
typedef __attribute__((ext_vector_type(4))) float f32x4;

static __device__ inline unsigned short f2bf(float f) {
    // round-to-nearest-even bf16
    unsigned int u = __float_as_uint(f);
    unsigned int rounded = u + 0x7fff + ((u >> 16) & 1);
    return (unsigned short)(rounded >> 16);
}

// ---------------- K1: renorm + prepack weights into MFMA fragment order (~3 us) -------
__global__ __launch_bounds__(64) void wfrag_kernel(const float* __restrict__ w,
                                                   uint4* __restrict__ wfrag) {
    const int oc   = blockIdx.x;
    const int lane = threadIdx.x;
    const float* wr = w + oc * 147;

    float ssq = 0.f;
    for (int k = lane; k < 147; k += 64) {
        float v = wr[k];
        ssq += v * v;
    }
    #pragma unroll
    for (int off = 32; off > 0; off >>= 1) ssq += __shfl_xor(ssq, off, 64);
    const float rms   = sqrtf(ssq * (1.0f / 147.0f));
    const float scale = (rms > 0.1f) ? (0.1f / rms) : 1.0f;

    if (lane < 24) {
        const int ch = lane >> 2;
        const int u  = lane & 3;
        const int U  = ch * 4 + u;
        unsigned short h[8];
        #pragma unroll
        for (int j = 0; j < 8; ++j) {
            float val = 0.f;
            if (U < 21 && j < 7) {
                int c  = U / 7;
                int kh = U - 7 * c;
                val = wr[c * 49 + kh * 7 + j] * scale;
            }
            h[j] = f2bf(val);
        }
        uint4 o;
        o.x = (unsigned)h[0] | ((unsigned)h[1] << 16);
        o.y = (unsigned)h[2] | ((unsigned)h[3] << 16);
        o.z = (unsigned)h[4] | ((unsigned)h[5] << 16);
        o.w = (unsigned)h[6] | ((unsigned)h[7] << 16);
        const int oct = oc >> 4;
        wfrag[((oct * 6 + ch) * 64) + (u * 16) + (oc & 15)] = o;
    }
}

// ---------------- K2: conv via bf16 MFMA — oc-split (R14-proven best config) ----------
// Block = 48 ocs (half) x (16 ow x 16 oh). LDS 36.2 KB -> 4 blocks/CU.
// NOTE (R15): oh-32 tile + packed cvt regressed +6us (fewer blocks, longer per-block
// prologue — conv is prologue-latency-bound). Keep this exact shape.
#define PROWS 37
#define PCOLS 40
#define CSTR  (PROWS * PCOLS)   // 1480

__global__ __launch_bounds__(512, 8) void conv_mfma_kernel(const float* __restrict__ x,
                                                           const uint4* __restrict__ wfrag,
                                                           const float* __restrict__ bias,
                                                           unsigned short* __restrict__ ypb) {
    __shared__ float patch[3 * CSTR];     // 17.8 KB
    __shared__ uint4 swf[18 * 64];        // 18.4 KB  (this block's 48-oc half)

    const int tid  = threadIdx.x;
    const int bx   = blockIdx.x;          // 49 px tiles
    const int img  = blockIdx.y;
    const int hf   = blockIdx.z;          // oc half: octs {3hf, 3hf+1, 3hf+2}
    const int tx = bx % 7, ty = bx / 7;
    const int ow0 = 16 * tx, oh0 = 16 * ty;
    const int ih0 = 2 * oh0 - 3, iwb = 2 * ow0 - 3;
    const float* xim = x + (size_t)img * 3 * IH * IW;

    // ---- stage this half's weight fragments (contiguous 18.4 KB) ----
    {
        const uint4* src = wfrag + hf * (18 * 64);
        for (int i = tid; i < 18 * 64; i += 512) swf[i] = src[i];
    }

    // ---- stage f32 patch [3][37][40] ----
    for (int i = tid; i < 3 * CSTR; i += 512) {
        int c   = i / CSTR;
        int rem = i - c * CSTR;
        int r   = rem / PCOLS;
        int cc  = rem - r * PCOLS;
        int ih = ih0 + r, iw = iwb + cc;
        float v = 0.f;
        if ((unsigned)ih < IH && (unsigned)iw < IW) v = xim[(c * IH + ih) * IW + iw];
        patch[i] = v;
    }

    const int wv   = tid >> 6;
    const int lane = tid & 63;
    const int m    = lane & 15;
    const int u    = lane >> 4;

    f32x4 acc[3][2];
    #pragma unroll
    for (int a = 0; a < 3; ++a)
        #pragma unroll
        for (int nt = 0; nt < 2; ++nt) acc[a][nt] = (f32x4){0.f, 0.f, 0.f, 0.f};

    __syncthreads();

    #pragma unroll 1
    for (int ch = 0; ch < 6; ++ch) {
        const int U   = 4 * ch + u;
        const int cq  = (U >= 7) + (U >= 14);
        const int khq = U - 7 * cq;
        const int rbase = (U < 21) ? (cq * CSTR + khq * PCOLS) : 0;

        bf16x8 xfr[2];
        #pragma unroll
        for (int nt = 0; nt < 2; ++nt) {
            const int ohl = 2 * wv + nt;
            const float* bp = &patch[rbase + ohl * 80 + 2 * m];
            float2 p0 = *(const float2*)(bp + 0);
            float2 p1 = *(const float2*)(bp + 2);
            float2 p2 = *(const float2*)(bp + 4);
            float2 p3 = *(const float2*)(bp + 6);
            xfr[nt][0] = (short)f2bf(p0.x); xfr[nt][1] = (short)f2bf(p0.y);
            xfr[nt][2] = (short)f2bf(p1.x); xfr[nt][3] = (short)f2bf(p1.y);
            xfr[nt][4] = (short)f2bf(p2.x); xfr[nt][5] = (short)f2bf(p2.y);
            xfr[nt][6] = (short)f2bf(p3.x); xfr[nt][7] = (short)f2bf(p3.y);
        }
        #pragma unroll
        for (int a = 0; a < 3; ++a) {
            uint4 wc = swf[(a * 6 + ch) * 64 + lane];
            bf16x8 wfr = *(bf16x8*)&wc;
            acc[a][0] = __builtin_amdgcn_mfma_f32_16x16x32_bf16(xfr[0], wfr, acc[a][0], 0, 0, 0);
            acc[a][1] = __builtin_amdgcn_mfma_f32_16x16x32_bf16(xfr[1], wfr, acc[a][1], 0, 0, 0);
        }
    }

    const int ow = ow0 + u * 4;
    #pragma unroll
    for (int a = 0; a < 3; ++a) {
        const int oc = (hf * 3 + a) * 16 + m;
        const float bv = bias[oc];
        #pragma unroll
        for (int nt = 0; nt < 2; ++nt) {
            const int oh = oh0 + 2 * wv + nt;
            unsigned short h0 = f2bf(acc[a][nt][0] + bv);
            unsigned short h1 = f2bf(acc[a][nt][1] + bv);
            unsigned short h2 = f2bf(acc[a][nt][2] + bv);
            unsigned short h3 = f2bf(acc[a][nt][3] + bv);
            uint2 st;
            st.x = (unsigned)h0 | ((unsigned)h1 << 16);
            st.y = (unsigned)h2 | ((unsigned)h3 << 16);
            *(uint2*)(ypb + (((size_t)img * OC + oc) * OHH + oh) * OWW + ow) = st;
        }
    }
}

// ---------------- K3: LDS-free fused LCN + relu + maxpool (R12-proven config) ---------
__global__ __launch_bounds__(256, 4) void lcn_pool_kernel(const unsigned short* __restrict__ y,
                                                          float* __restrict__ outp,
                                                          float* __restrict__ prep,
                                                          float* __restrict__ idxp) {
    const int tid   = threadIdx.x;
    const int band  = tid >> 6;
    const int lane  = tid & 63;
    const int plane = blockIdx.x;
    const int r0    = band * 28;
    const int c0    = lane * 2;
    const bool colv = (lane < 56);

    const unsigned short* yp = y + (size_t)plane * (OHH * OWW);
    float* pp  = prep + (size_t)plane * (OHH * OWW);
    float* op_ = outp + (size_t)plane * (56 * 56);
    float* ip_ = idxp + (size_t)plane * (56 * 56);

    const int lm = (lane + 63) & 63;
    const int lp = (lane + 1) & 63;

    float2 hs0{0,0}, hs1{0,0}, hs2{0,0}, hs3{0,0}, hs4{0,0};
    float2 q0{0,0},  q1{0,0},  q2{0,0},  q3{0,0},  q4{0,0};
    float2 y0{0,0},  y1{0,0},  y2{0,0};
    float2 ct0{0,0}, ct1{0,0}, ct2{0,0};
    float2 prev{0,0};

    #pragma unroll
    for (int i = 0; i < 36; ++i) {
        const int irow = r0 - 4 + i;
        float2 v = {0.f, 0.f};
        if ((unsigned)irow < OHH && colv) {
            unsigned int pr = *(const unsigned int*)(yp + irow * OWW + c0);
            v.x = __uint_as_float(pr << 16);
            v.y = __uint_as_float(pr & 0xffff0000u);
        }

        float Lx = __shfl(v.x, lm, 64), Ly = __shfl(v.y, lm, 64);
        float Rx = __shfl(v.x, lp, 64), Ry = __shfl(v.y, lp, 64);
        float2 hs_new;
        hs_new.x = Lx + Ly + v.x + v.y + Rx;
        hs_new.y = Ly + v.x + v.y + Rx + Ry;
        hs0 = hs1; hs1 = hs2; hs2 = hs3; hs3 = hs4; hs4 = hs_new;
        y0 = y1; y1 = y2; y2 = v;

        if (i >= 4) {
            const int mrow = irow - 2;
            float2 mean;
            mean.x = (hs0.x + hs1.x + hs2.x + hs3.x + hs4.x) * 0.04f;
            mean.y = (hs0.y + hs1.y + hs2.y + hs3.y + hs4.y) * 0.04f;
            float2 ct;
            ct.x = y0.x - mean.x;
            ct.y = y0.y - mean.y;
            if ((unsigned)mrow >= OHH || !colv) { ct.x = 0.f; ct.y = 0.f; }

            float cLx = __shfl(ct.x, lm, 64), cLy = __shfl(ct.y, lm, 64);
            float cRx = __shfl(ct.x, lp, 64), cRy = __shfl(ct.y, lp, 64);
            float2 q_new;
            q_new.x = cLx*cLx + cLy*cLy + ct.x*ct.x + ct.y*ct.y + cRx*cRx;
            q_new.y = cLy*cLy + ct.x*ct.x + ct.y*ct.y + cRx*cRx + cRy*cRy;
            q0 = q1; q1 = q2; q2 = q3; q3 = q4; q4 = q_new;
            ct0 = ct1; ct1 = ct2; ct2 = ct;

            if (i >= 8) {
                const int o = irow - 4;
                float sx = q0.x + q1.x + q2.x + q3.x + q4.x;
                float sy = q0.y + q1.y + q2.y + q3.y + q4.y;
                float vx = fmaxf(ct0.x * rsqrtf(fmaf(sx, 0.04f, 1.0f)), 0.f);
                float vy = fmaxf(ct0.y * rsqrtf(fmaf(sy, 0.04f, 1.0f)), 0.f);
                if (colv) {
                    float2 pv = {vx, vy};
                    *(float2*)(pp + o * OWW + c0) = pv;
                }
                if (o & 1) {
                    float best = prev.x; int loc = 0;
                    if (prev.y > best) { best = prev.y; loc = 1; }
                    if (vx     > best) { best = vx;     loc = 2; }
                    if (vy     > best) { best = vy;     loc = 3; }
                    int idx = (o - 1 + (loc >> 1)) * OWW + (c0 + (loc & 1));
                    if (colv) {
                        size_t oo = (size_t)(o >> 1) * 56 + lane;
                        op_[oo] = best;
                        ip_[oo] = (float)idx;
                    }
                }
                prev.x = vx; prev.y = vy;
            }
        }
    }
}

extern "C" void kernel_launch(void* const* d_in, const int* in_sizes, int n_in,
                              void* d_out, int out_size, void* d_ws, size_t ws_size,
                              hipStream_t stream) {
    const float* x    = (const float*)d_in[0];
    const float* w    = (const float*)d_in[1];
    const float* bias = (const float*)d_in[2];

    unsigned short* y = (unsigned short*)d_ws;                  // 19,267,584 bf16 = 38.5 MB
    uint4* wfrag = (uint4*)((char*)d_ws + (size_t)NIMG * OC * OHH * OWW * 2);  // 36,864 B

    float* outp = (float*)d_out;                                // [16,96,56,56]
    float* prep = outp + (size_t)NIMG * OC * 56 * 56;           // [16,96,112,112]
    float* idxp = prep + (size_t)NIMG * OC * OHH * OWW;         // [16,96,56,56]

    wfrag_kernel<<<dim3(OC), dim3(64), 0, stream>>>(w, wfrag);
    conv_mfma_kernel<<<dim3(49, NIMG, 2), dim3(512), 0, stream>>>(x, wfrag, bias, y);
    lcn_pool_kernel<<<dim3(NIMG * OC), dim3(256), 0, stream>>>(y, outp, prep, idxp);
}